// Round 10
// baseline (610.709 us; speedup 1.0000x reference)
//
#include <hip/hip_runtime.h>
#include <stdint.h>

typedef unsigned short u16;
typedef unsigned int u32;
typedef unsigned long long u64;

typedef __attribute__((ext_vector_type(8))) short bfrag;   // 8 bf16 (4 VGPRs)
typedef __attribute__((ext_vector_type(4))) float f32x4;   // 4 fp32 acc

// ---------- bf16 helpers (OCP bf16 = raw upper 16 bits of fp32) ----------
__device__ __forceinline__ float bf2f(u16 u) { return __uint_as_float(((u32)u) << 16); }
__device__ __forceinline__ u16 f2bf(float f) {
    u32 i = __float_as_uint(f);
    u32 r = i + 0x7fffu + ((i >> 16) & 1u);   // round-to-nearest-even
    return (u16)(r >> 16);
}
__device__ __forceinline__ u32 pack2(float a, float b) {
    return (u32)f2bf(a) | ((u32)f2bf(b) << 16);
}
__device__ __forceinline__ float lo16(u32 u) { return __uint_as_float(u << 16); }
__device__ __forceinline__ float hi16(u32 u) { return __uint_as_float(u & 0xffff0000u); }
#define RFL(x) __builtin_amdgcn_readfirstlane(x)

// 16-lane (row) sum via DPP row_ror rotate-adds.
#define DPP_ROR_ADD(p, ctrl) \
    p += __int_as_float(__builtin_amdgcn_update_dpp(0, __float_as_int(p), ctrl, 0xF, 0xF, false))
__device__ __forceinline__ float red16(float p) {
    DPP_ROR_ADD(p, 0x128);   // ror 8
    DPP_ROR_ADD(p, 0x124);   // ror 4
    DPP_ROR_ADD(p, 0x122);   // ror 2
    DPP_ROR_ADD(p, 0x121);   // ror 1
    return p;                // every lane in the 16-row holds the row sum
}

// ---------- CSR build ----------
// rank_hist: one atomic per edge counts degree AND yields the edge's slot-rank.
__global__ void rank_hist(const int* __restrict__ dst, int E,
                          int* __restrict__ deg, int* __restrict__ rank) {
    int e = blockIdx.x * blockDim.x + threadIdx.x;
    if (e < E) rank[e] = atomicAdd(&deg[dst[e]], 1);
}

#define SCAN_T 256
#define SCAN_E 8
#define SCAN_CHUNK 2048

__global__ void scan_partial(const int* __restrict__ deg, int n, int* __restrict__ partials) {
    __shared__ int sh[SCAN_T];
    int b = blockIdx.x, t = threadIdx.x;
    int base = b * SCAN_CHUNK + t * SCAN_E;
    int s = 0;
#pragma unroll
    for (int i = 0; i < SCAN_E; i++) { int idx = base + i; if (idx < n) s += deg[idx]; }
    sh[t] = s; __syncthreads();
    for (int off = SCAN_T / 2; off > 0; off >>= 1) {
        if (t < off) sh[t] += sh[t + off];
        __syncthreads();
    }
    if (t == 0) partials[b] = sh[0];
}

__global__ void scan_mid(int* __restrict__ partials, int nb) {
    if (threadIdx.x == 0 && blockIdx.x == 0) {
        int acc = 0;
        for (int i = 0; i < nb; i++) { int v = partials[i]; partials[i] = acc; acc += v; }
    }
}

__global__ void scan_final(const int* __restrict__ deg, int n, const int* __restrict__ partials,
                           int* __restrict__ offs, int E) {
    __shared__ int sh[SCAN_T];
    int b = blockIdx.x, t = threadIdx.x;
    int base = b * SCAN_CHUNK + t * SCAN_E;
    int loc[SCAN_E];
    int s = 0;
#pragma unroll
    for (int i = 0; i < SCAN_E; i++) {
        int idx = base + i;
        int v = (idx < n) ? deg[idx] : 0;
        loc[i] = s; s += v;
    }
    sh[t] = s; __syncthreads();
    for (int off = 1; off < SCAN_T; off <<= 1) {
        int v = 0;
        if (t >= off) v = sh[t - off];
        __syncthreads();
        if (t >= off) sh[t] += v;
        __syncthreads();
    }
    int tbase = partials[b] + sh[t] - s;   // exclusive base for this thread
#pragma unroll
    for (int i = 0; i < SCAN_E; i++) { int idx = base + i; if (idx < n) offs[idx] = tbase + loc[i]; }
    if (b == gridDim.x - 1 && t == SCAN_T - 1) offs[n] = E;
}

// ---------- fill_eid: the ONLY scatter in the pipeline -- 4B per edge ----------
// Scatters pay partial-line RMW; keeping the scattered payload at 4B minimizes it.
__global__ void fill_eid(const int* __restrict__ dstv,
                         const int* __restrict__ rank,
                         const int* __restrict__ offs, int E,
                         int* __restrict__ ceid) {
    int e = blockIdx.x * blockDim.x + threadIdx.x;
    if (e >= E) return;
    ceid[offs[dstv[e]] + rank[e]] = e;
}

// ---------- gather_fill: CSR-order pass, all writes coalesced ----------
// p coalesced; e=ceid[p]; random READS of ea/srcv (L3/L2-resident, no RMW cost);
// writes cattr (CSR-ordered bf16 attrs) + csrc fully coalesced. This converts the
// attr permutation from scatter (r5: ~95us RMW) to gather (+no scatter at all).
__global__ void gather_fill(const int* __restrict__ ceid,
                            const int* __restrict__ srcv,
                            const float4* __restrict__ ea, int E,
                            int* __restrict__ csrc, uint4* __restrict__ cattr) {
    int p = blockIdx.x * blockDim.x + threadIdx.x;
    if (p >= E) return;
    int e = ceid[p];
    const float4* s = ea + (u64)e * 4;
    float4 v0 = s[0], v1 = s[1], v2 = s[2], v3 = s[3];
    cattr[(u64)p * 2]     = make_uint4(pack2(v0.x, v0.y), pack2(v0.z, v0.w),
                                       pack2(v1.x, v1.y), pack2(v1.z, v1.w));
    cattr[(u64)p * 2 + 1] = make_uint4(pack2(v2.x, v2.y), pack2(v2.z, v2.w),
                                       pack2(v3.x, v3.y), pack2(v3.z, v3.w));
    csrc[p] = srcv[e];
}

// ---------- ALL weight pre-packs in one launch ----------
// [0,2048): Wl1|Wr1 (K=128) -> wb1 ; [2048,3072): Wl2|Wr2 (K=64) -> wb2 ;
// [3072,3328): We1 -> web1 ; [3328,3584): We2 -> web2.
__device__ __forceinline__ void pack_w_job(const float* Wl, const float* Wr, u32* Wb,
                                           int t, int NKS) {
    int lane = t & 63;
    int ks = (t >> 6) % NKS;
    int ct = (t >> 6) / NKS;
    int n = lane & 15, quad = lane >> 4;
    int c = ct * 16 + n;
    const float* W = (c < 64) ? Wl : Wr;
    int cc = c & 63;
    u32* d = Wb + (u64)t * 4;
#pragma unroll
    for (int p = 0; p < 4; p++) {
        int k0 = ks * 32 + quad * 8 + 2 * p;
        d[p] = pack2(W[(u64)k0 * 64 + cc], W[(u64)(k0 + 1) * 64 + cc]);
    }
}
__device__ __forceinline__ void pack_we_job(const float* We, u32* web, int t) {
    int lane = t & 63, ct = t >> 6;
    int n = lane & 15, quad = lane >> 4;
    int c = ct * 16 + n;
    u32* d = web + (u64)t * 4;
#pragma unroll
    for (int p = 0; p < 4; p++) {
        int k0 = quad * 8 + 2 * p;
        d[p] = (k0 + 1 < 16) ? pack2(We[(u64)k0 * 64 + c], We[(u64)(k0 + 1) * 64 + c]) : 0u;
    }
}
__global__ void pack_all(const float* __restrict__ Wl1, const float* __restrict__ Wr1,
                         const float* __restrict__ Wl2, const float* __restrict__ Wr2,
                         const float* __restrict__ We1, const float* __restrict__ We2,
                         u32* __restrict__ wb1, u32* __restrict__ wb2,
                         u32* __restrict__ web1, u32* __restrict__ web2) {
    int t = blockIdx.x * blockDim.x + threadIdx.x;
    if (t < 2048)       pack_w_job(Wl1, Wr1, wb1, t, 4);
    else if (t < 3072)  pack_w_job(Wl2, Wr2, wb2, t - 2048, 2);
    else if (t < 3328)  pack_we_job(We1, web1, t - 3072);
    else if (t < 3584)  pack_we_job(We2, web2, t - 3328);
}

// ---------- MFMA dual GEMM: [xl|xr] = X @ [Wl|Wr] + [bl|br] (bf16 out) ----------
// Output layout PERMUTED for gat gathers: buf[row][m*4+ct] -> one dwordx2 per gather.
template <int K, bool XF32>
__global__ __launch_bounds__(256) void gemm_mfma(const void* __restrict__ Xv,
                                                 const u32* __restrict__ Wb,
                                                 const float* __restrict__ bl,
                                                 const float* __restrict__ br,
                                                 int N, u16* __restrict__ xl, u16* __restrict__ xr) {
    constexpr int NKS = K / 32;
    int lane = threadIdx.x & 63;
    int gw = (blockIdx.x * 256 + threadIdx.x) >> 6;
    int row0 = gw * 16;
    if (row0 >= N) return;
    int m = lane & 15, quad = lane >> 4;

    f32x4 acc[8];
#pragma unroll
    for (int ct = 0; ct < 8; ct++) acc[ct] = (f32x4){0.f, 0.f, 0.f, 0.f};

#pragma unroll
    for (int ks = 0; ks < NKS; ks++) {
        bfrag a;
        if (XF32) {
            const float* xp = (const float*)Xv + (u64)(row0 + m) * K + ks * 32 + quad * 8;
            float4 v0 = *(const float4*)xp;
            float4 v1 = *(const float4*)(xp + 4);
            union { bfrag v; u32 d[4]; } au;
            au.d[0] = pack2(v0.x, v0.y); au.d[1] = pack2(v0.z, v0.w);
            au.d[2] = pack2(v1.x, v1.y); au.d[3] = pack2(v1.z, v1.w);
            a = au.v;
        } else {
            a = *(const bfrag*)((const u16*)Xv + (u64)(row0 + m) * K + ks * 32 + quad * 8);
        }
#pragma unroll
        for (int ct = 0; ct < 8; ct++) {
            bfrag b = *(const bfrag*)(Wb + (u64)((ct * NKS + ks) * 64 + lane) * 4);
            acc[ct] = __builtin_amdgcn_mfma_f32_16x16x32_bf16(a, b, acc[ct], 0, 0, 0);
        }
    }

    float bvl[4], bvr[4];
#pragma unroll
    for (int ct = 0; ct < 4; ct++) { bvl[ct] = bl[ct * 16 + m]; bvr[ct] = br[ct * 16 + m]; }
#pragma unroll
    for (int r = 0; r < 4; r++) {
        int row = row0 + quad * 4 + r;
        uint2 ql, qr;
        ql.x = pack2(acc[0][r] + bvl[0], acc[1][r] + bvl[1]);
        ql.y = pack2(acc[2][r] + bvl[2], acc[3][r] + bvl[3]);
        qr.x = pack2(acc[4][r] + bvr[0], acc[5][r] + bvr[1]);
        qr.y = pack2(acc[6][r] + bvr[2], acc[7][r] + bvr[3]);
        *(uint2*)(xl + (u64)row * 64 + m * 4) = ql;
        *(uint2*)(xr + (u64)row * 64 + m * 4) = qr;
    }
}

// ---------- GATv2 layer: MFMA edge-attr transform, CSR-ordered attrs ----------
// EE[16e x 64c] = EA[16x16] @ We[16x64] via 4x mfma_f32_16x16x32_bf16 (K zero-padded
// to 32). xr folded into MFMA C-operand (broadcast over rows); invalid tail rows then
// produce ee=xr exactly, so eesum = sum(eeX)-4*xr stays exact. A-frag reads cattr[slot]
// DIRECTLY (CSR-ordered bf16: sequential, coalesced -- r5's locality) -- no eid shfl.
// csrc preload is 4B/slot. xl/xr PERMUTED [row][m*4+ct] -> each src gather ONE dwordx2.
// D layout: lane(quad,m) reg r -> edge=quad*4+r, chan=ct*16+m.
__global__ __launch_bounds__(256) void gat_layer(const u16* __restrict__ xl, const u16* __restrict__ xr,
                                                 const int* __restrict__ offs,
                                                 const int* __restrict__ csrc,   // src per CSR slot
                                                 const u32* __restrict__ cattr,  // 16 bf16 per CSR slot
                                                 const u32* __restrict__ web,    // packed We B-frags
                                                 const float* __restrict__ att,  // 64, fp32
                                                 const float* __restrict__ bias, // 64, fp32
                                                 int N, u16* __restrict__ out) {
    const float LOG2E = 1.44269504088896340736f;
    int l = threadIdx.x & 63;
    int m = l & 15, quad = l >> 4;
    int wid = RFL((int)((blockIdx.x * 256 + threadIdx.x) >> 6));
    int nw = gridDim.x * 4;

    bfrag wb[4];
#pragma unroll
    for (int ct = 0; ct < 4; ct++) wb[ct] = *(const bfrag*)(web + (u64)(ct * 64 + l) * 4);

    float att_l = att[l] * LOG2E;
    float att_f[4];
#pragma unroll
    for (int ct = 0; ct < 4; ct++) att_f[ct] = att[ct * 16 + m] * LOG2E;
    float bias_l = bias[l];

    for (int n = wid; n < N; n += nw) {
        int a = RFL(offs[n]);
        int b = RFL(offs[n + 1]);
        float xr_l = bf2f(xr[(u32)(n * 64 + m * 4 + quad)]);
        float xl_self = bf2f(xl[(u32)(n * 64 + m * 4 + quad)]);
        uint2 qxr = *(const uint2*)(xr + (u32)(n * 64 + m * 4));
        float xr_f[4] = {lo16(qxr.x), hi16(qxr.x), lo16(qxr.y), hi16(qxr.y)};

        float o_f[4] = {0.f, 0.f, 0.f, 0.f};
        float ls_f[4] = {0.f, 0.f, 0.f, 0.f};
        float ee_f[4] = {0.f, 0.f, 0.f, 0.f};

        for (int base = a; base < b; base += 64) {
            int cnt64 = b - base; if (cnt64 > 64) cnt64 = 64;
            int idx = base + l;
            int sv = csrc[idx < b ? idx : b - 1];    // coalesced per-lane preload

            for (int j = 0; j < cnt64; j += 16) {
                int cnt = cnt64 - j; if (cnt > 16) cnt = 16;
                // --- A-frag: direct CSR-ordered cattr read (coalesced) ---
                union { bfrag v; u32 d[4]; } au;
                au.d[0] = 0; au.d[1] = 0; au.d[2] = 0; au.d[3] = 0;
                if (quad < 2 && m < cnt)
                    au.v = *(const bfrag*)(cattr + (u64)(base + j + m) * 8 + quad * 4);
                // --- this quad's 4 srcs; one dwordx2 gather each ---
                int jq = j + quad * 4;
                int sr0 = __shfl(sv, jq);
                int sr1 = __shfl(sv, jq + 1);
                int sr2 = __shfl(sv, jq + 2);
                int sr3 = __shfl(sv, jq + 3);
                uint2 g0 = *(const uint2*)(xl + (u32)(sr0 * 64 + m * 4));
                uint2 g1 = *(const uint2*)(xl + (u32)(sr1 * 64 + m * 4));
                uint2 g2 = *(const uint2*)(xl + (u32)(sr2 * 64 + m * 4));
                uint2 g3 = *(const uint2*)(xl + (u32)(sr3 * 64 + m * 4));
                float xv[4][4];
                xv[0][0] = lo16(g0.x); xv[0][1] = hi16(g0.x); xv[0][2] = lo16(g0.y); xv[0][3] = hi16(g0.y);
                xv[1][0] = lo16(g1.x); xv[1][1] = hi16(g1.x); xv[1][2] = lo16(g1.y); xv[1][3] = hi16(g1.y);
                xv[2][0] = lo16(g2.x); xv[2][1] = hi16(g2.x); xv[2][2] = lo16(g2.y); xv[2][3] = hi16(g2.y);
                xv[3][0] = lo16(g3.x); xv[3][1] = hi16(g3.x); xv[3][2] = lo16(g3.y); xv[3][3] = hi16(g3.y);
                // --- MFMA: ee = EA @ We + xr (xr broadcast over rows via C) ---
                f32x4 ee[4];
#pragma unroll
                for (int ct = 0; ct < 4; ct++) {
                    f32x4 c = (f32x4){xr_f[ct], xr_f[ct], xr_f[ct], xr_f[ct]};
                    ee[ct] = __builtin_amdgcn_mfma_f32_16x16x32_bf16(au.v, wb[ct], c, 0, 0, 0);
                }
                // --- eesum (raw ee): invalid rows give eeX = xr exactly ---
#pragma unroll
                for (int ct = 0; ct < 4; ct++)
                    ee_f[ct] += (ee[ct][0] + ee[ct][1]) + (ee[ct][2] + ee[ct][3]) - 4.f * xr_f[ct];
                // --- z, leaky, att-scale ---
                float zz[4][4];
#pragma unroll
                for (int ct = 0; ct < 4; ct++) {
#pragma unroll
                    for (int r = 0; r < 4; r++) {
                        float z = ee[ct][r] + xv[r][ct];
                        z = fmaxf(z, 0.2f * z);
                        zz[ct][r] = z * att_f[ct];
                    }
                }
                // --- 16 interleaved red16 (DPP hazards hidden) ---
#define R16(ctrl) { \
    DPP_ROR_ADD(zz[0][0], ctrl); DPP_ROR_ADD(zz[0][1], ctrl); DPP_ROR_ADD(zz[0][2], ctrl); DPP_ROR_ADD(zz[0][3], ctrl); \
    DPP_ROR_ADD(zz[1][0], ctrl); DPP_ROR_ADD(zz[1][1], ctrl); DPP_ROR_ADD(zz[1][2], ctrl); DPP_ROR_ADD(zz[1][3], ctrl); \
    DPP_ROR_ADD(zz[2][0], ctrl); DPP_ROR_ADD(zz[2][1], ctrl); DPP_ROR_ADD(zz[2][2], ctrl); DPP_ROR_ADD(zz[2][3], ctrl); \
    DPP_ROR_ADD(zz[3][0], ctrl); DPP_ROR_ADD(zz[3][1], ctrl); DPP_ROR_ADD(zz[3][2], ctrl); DPP_ROR_ADD(zz[3][3], ctrl); }
                R16(0x128) R16(0x124) R16(0x122) R16(0x121)
#undef R16
                // --- exp (pre-scaled by log2e -> raw v_exp_f32) ---
                float w[4][4];
#pragma unroll
                for (int ct = 0; ct < 4; ct++) {
#pragma unroll
                    for (int r = 0; r < 4; r++)
                        asm("v_exp_f32 %0, %1" : "=v"(w[ct][r]) : "v"(zz[ct][r]));
                }
                // --- tail mask: zero weights of invalid rows ---
                if (cnt < 16) {
#pragma unroll
                    for (int r = 0; r < 4; r++) {
                        bool ok = (quad * 4 + r) < cnt;
#pragma unroll
                        for (int ct = 0; ct < 4; ct++) w[ct][r] = ok ? w[ct][r] : 0.f;
                    }
                }
                // --- accumulate ---
#pragma unroll
                for (int ct = 0; ct < 4; ct++) {
#pragma unroll
                    for (int r = 0; r < 4; r++) {
                        ls_f[ct] += w[ct][r];
                        o_f[ct] = fmaf(w[ct][r], xv[r][ct], o_f[ct]);
                    }
                }
            }
        }

        // --- cross-quad reduction (edges split 4 per quad) ---
#pragma unroll
        for (int ct = 0; ct < 4; ct++) {
            o_f[ct] += __shfl_xor(o_f[ct], 16);  o_f[ct] += __shfl_xor(o_f[ct], 32);
            ls_f[ct] += __shfl_xor(ls_f[ct], 16); ls_f[ct] += __shfl_xor(ls_f[ct], 32);
            ee_f[ct] += __shfl_xor(ee_f[ct], 16); ee_f[ct] += __shfl_xor(ee_f[ct], 32);
        }
        float o    = (quad & 2) ? ((quad & 1) ? o_f[3] : o_f[2]) : ((quad & 1) ? o_f[1] : o_f[0]);
        float lsum = (quad & 2) ? ((quad & 1) ? ls_f[3] : ls_f[2]) : ((quad & 1) ? ls_f[1] : ls_f[0]);
        float eesum= (quad & 2) ? ((quad & 1) ? ee_f[3] : ee_f[2]) : ((quad & 1) ? ee_f[1] : ee_f[0]);

        // --- self-loop: ee = eesum/deg (mean edge-attr transform), src = n ---
        int deg = b - a;
        float inv = (deg > 0) ? 1.f / (float)deg : 0.f;
        float z = (eesum * inv + xr_l) + xl_self;
        z = fmaxf(z, 0.2f * z);
        float vv = red16(z * att_l);
        float ws;
        asm("v_exp_f32 %0, %1" : "=v"(ws) : "v"(vv));
        lsum += ws;
        o = fmaf(ws, xl_self, o);

        float res = o / (lsum + 1e-16f) + bias_l;
        res = fmaxf(res, 0.f);                        // relu after each GAT layer
        out[(u32)(n * 64 + l)] = f2bf(res);           // natural order (feeds GEMM/MLP)
    }
}

// ---------- MLP head: relu(h @ W1 + b1) @ W2 + b2 -> sigmoid (fp32 out) ----------
__global__ __launch_bounds__(256) void mlp_head(const u16* __restrict__ h,
                                                const float* __restrict__ W1, const float* __restrict__ b1,
                                                const float* __restrict__ W2, const float* __restrict__ b2,
                                                int N, float* __restrict__ out) {
    __shared__ float w1[64 * 16];
    __shared__ float sb1[16];
    __shared__ float w2[16];
    for (int i = threadIdx.x; i < 64 * 16; i += 256) w1[i] = W1[i];
    if (threadIdx.x < 16) { sb1[threadIdx.x] = b1[threadIdx.x]; w2[threadIdx.x] = W2[threadIdx.x]; }
    __syncthreads();
    float b2v = b2[0];
    int n = blockIdx.x * blockDim.x + threadIdx.x;
    if (n < N) {
        float hv[64];
        const u32* hp = (const u32*)(h + (u64)n * 64);
#pragma unroll
        for (int i = 0; i < 32; i++) { u32 u = hp[i]; hv[2 * i] = lo16(u); hv[2 * i + 1] = hi16(u); }
        float z = b2v;
        for (int j = 0; j < 16; j++) {
            float acc = sb1[j];
#pragma unroll
            for (int k = 0; k < 64; k++) acc = fmaf(hv[k], w1[k * 16 + j], acc);
            acc = fmaxf(acc, 0.f);
            z = fmaf(acc, w2[j], z);
        }
        out[n] = 1.f / (1.f + __expf(-z));
    }
}

// ---------- launch ----------
extern "C" void kernel_launch(void* const* d_in, const int* in_sizes, int n_in,
                              void* d_out, int out_size, void* d_ws, size_t ws_size,
                              hipStream_t stream) {
    const float* x    = (const float*)d_in[0];
    const int*   ei   = (const int*)d_in[1];
    const float* ea   = (const float*)d_in[2];
    const float* Wl1  = (const float*)d_in[3];
    const float* bl1  = (const float*)d_in[4];
    const float* Wr1  = (const float*)d_in[5];
    const float* br1  = (const float*)d_in[6];
    const float* We1  = (const float*)d_in[7];
    const float* att1 = (const float*)d_in[8];
    const float* bias1= (const float*)d_in[9];
    const float* Wl2  = (const float*)d_in[10];
    const float* bl2  = (const float*)d_in[11];
    const float* Wr2  = (const float*)d_in[12];
    const float* br2  = (const float*)d_in[13];
    const float* We2  = (const float*)d_in[14];
    const float* att2 = (const float*)d_in[15];
    const float* bias2= (const float*)d_in[16];
    const float* W1   = (const float*)d_in[17];
    const float* b1   = (const float*)d_in[18];
    const float* W2   = (const float*)d_in[19];
    const float* b2   = (const float*)d_in[20];
    float* out = (float*)d_out;

    const int N = in_sizes[0] / 128;
    const int E = in_sizes[1] / 2;
    const int* srcv = ei;
    const int* dstv = ei + E;

    uint8_t* p = (uint8_t*)d_ws;
    auto carve = [&](size_t bytes) -> void* {
        void* r = (void*)p;
        p += (bytes + 255) & ~(size_t)255;
        return r;
    };
    int*  deg     = (int*)carve((size_t)N * 4);
    int*  rank    = (int*)carve((size_t)E * 4);
    int*  offs    = (int*)carve((size_t)(N + 1) * 4);
    int*  partials= (int*)carve(4096);
    int*  ceid    = (int*)carve((size_t)E * 4);     // eid per CSR slot (only scatter)
    int*  csrc    = (int*)carve((size_t)E * 4);     // src per CSR slot
    u32*  cattr   = (u32*)carve((size_t)E * 32);    // 16 bf16 per CSR slot
    u16*  xl      = (u16*)carve((size_t)N * 64 * 2);
    u16*  xr      = (u16*)carve((size_t)N * 64 * 2);
    u16*  hb      = (u16*)carve((size_t)N * 64 * 2);
    u32*  wb1     = (u32*)carve(8 * 4 * 64 * 16);   // K=128 packed W
    u32*  wb2     = (u32*)carve(8 * 2 * 64 * 16);   // K=64 packed W
    u32*  web1    = (u32*)carve(4 * 64 * 4 * 4);    // We1 B-frags
    u32*  web2    = (u32*)carve(4 * 64 * 4 * 4);    // We2 B-frags
    (void)ws_size; (void)n_in; (void)out_size;

    hipMemsetAsync(deg, 0, (size_t)N * 4, stream);

    const int B = 256;
    pack_all<<<14, 256, 0, stream>>>(Wl1, Wr1, Wl2, Wr2, We1, We2, wb1, wb2, web1, web2);
    rank_hist<<<(E + B - 1) / B, B, 0, stream>>>(dstv, E, deg, rank);
    int nb = (N + SCAN_CHUNK - 1) / SCAN_CHUNK;
    scan_partial<<<nb, SCAN_T, 0, stream>>>(deg, N, partials);
    scan_mid<<<1, 64, 0, stream>>>(partials, nb);
    scan_final<<<nb, SCAN_T, 0, stream>>>(deg, N, partials, offs, E);
    fill_eid<<<(E + B - 1) / B, B, 0, stream>>>(dstv, rank, offs, E, ceid);
    gather_fill<<<(E + B - 1) / B, B, 0, stream>>>(ceid, srcv, (const float4*)ea, E,
                                                   csrc, (uint4*)cattr);

    int gemm_blocks = (N / 16 + 3) / 4;
    // Layer 1
    gemm_mfma<128, true><<<gemm_blocks, 256, 0, stream>>>(x, wb1, bl1, br1, N, xl, xr);
    gat_layer<<<8192, 256, 0, stream>>>(xl, xr, offs, csrc, cattr, web1,
                                        att1, bias1, N, hb);
    // Layer 2
    gemm_mfma<64, false><<<gemm_blocks, 256, 0, stream>>>(hb, wb2, bl2, br2, N, xl, xr);
    gat_layer<<<8192, 256, 0, stream>>>(xl, xr, offs, csrc, cattr, web2,
                                        att2, bias2, N, hb);
    // Head
    mlp_head<<<(N + B - 1) / B, B, 0, stream>>>(hb, W1, b1, W2, b2, N, out);
}

// Round 11
// 541.479 us; speedup vs baseline: 1.1279x; 1.1279x over previous
//
#include <hip/hip_runtime.h>
#include <stdint.h>

typedef unsigned short u16;
typedef unsigned int u32;
typedef unsigned long long u64;

typedef __attribute__((ext_vector_type(8))) short bfrag;   // 8 bf16 (4 VGPRs)
typedef __attribute__((ext_vector_type(4))) float f32x4;   // 4 fp32 acc

// ---------- bf16 helpers (OCP bf16 = raw upper 16 bits of fp32) ----------
__device__ __forceinline__ float bf2f(u16 u) { return __uint_as_float(((u32)u) << 16); }
__device__ __forceinline__ u16 f2bf(float f) {
    u32 i = __float_as_uint(f);
    u32 r = i + 0x7fffu + ((i >> 16) & 1u);   // round-to-nearest-even
    return (u16)(r >> 16);
}
__device__ __forceinline__ u32 pack2(float a, float b) {
    return (u32)f2bf(a) | ((u32)f2bf(b) << 16);
}
__device__ __forceinline__ float lo16(u32 u) { return __uint_as_float(u << 16); }
__device__ __forceinline__ float hi16(u32 u) { return __uint_as_float(u & 0xffff0000u); }
#define RFL(x) __builtin_amdgcn_readfirstlane(x)

// 16-lane (row) sum via DPP row_ror rotate-adds.
#define DPP_ROR_ADD(p, ctrl) \
    p += __int_as_float(__builtin_amdgcn_update_dpp(0, __float_as_int(p), ctrl, 0xF, 0xF, false))
__device__ __forceinline__ float red16(float p) {
    DPP_ROR_ADD(p, 0x128);   // ror 8
    DPP_ROR_ADD(p, 0x124);   // ror 4
    DPP_ROR_ADD(p, 0x122);   // ror 2
    DPP_ROR_ADD(p, 0x121);   // ror 1
    return p;                // every lane in the 16-row holds the row sum
}

#define SCAN_T 256
#define SCAN_E 8
#define SCAN_CHUNK 2048

__global__ void scan_partial(const int* __restrict__ deg, int n, int* __restrict__ partials) {
    __shared__ int sh[SCAN_T];
    int b = blockIdx.x, t = threadIdx.x;
    int base = b * SCAN_CHUNK + t * SCAN_E;
    int s = 0;
#pragma unroll
    for (int i = 0; i < SCAN_E; i++) { int idx = base + i; if (idx < n) s += deg[idx]; }
    sh[t] = s; __syncthreads();
    for (int off = SCAN_T / 2; off > 0; off >>= 1) {
        if (t < off) sh[t] += sh[t + off];
        __syncthreads();
    }
    if (t == 0) partials[b] = sh[0];
}

__global__ void scan_mid(int* __restrict__ partials, int nb) {
    if (threadIdx.x == 0 && blockIdx.x == 0) {
        int acc = 0;
        for (int i = 0; i < nb; i++) { int v = partials[i]; partials[i] = acc; acc += v; }
    }
}

__global__ void scan_final(const int* __restrict__ deg, int n, const int* __restrict__ partials,
                           int* __restrict__ offs, int E) {
    __shared__ int sh[SCAN_T];
    int b = blockIdx.x, t = threadIdx.x;
    int base = b * SCAN_CHUNK + t * SCAN_E;
    int loc[SCAN_E];
    int s = 0;
#pragma unroll
    for (int i = 0; i < SCAN_E; i++) {
        int idx = base + i;
        int v = (idx < n) ? deg[idx] : 0;
        loc[i] = s; s += v;
    }
    sh[t] = s; __syncthreads();
    for (int off = 1; off < SCAN_T; off <<= 1) {
        int v = 0;
        if (t >= off) v = sh[t - off];
        __syncthreads();
        if (t >= off) sh[t] += v;
        __syncthreads();
    }
    int tbase = partials[b] + sh[t] - s;   // exclusive base for this thread
#pragma unroll
    for (int i = 0; i < SCAN_E; i++) { int idx = base + i; if (idx < n) offs[idx] = tbase + loc[i]; }
    if (b == gridDim.x - 1 && t == SCAN_T - 1) offs[n] = E;
}

// ---------- CSR fill: int2 {src, eid} per slot ----------
// r8 measured: eid-only (4B scatter) + srcv[eid] gather in gat costs 2.5x what the
// smaller scatter saves (gat 117.5->142.9us, FETCH +84MB). int2 is the optimum.
__global__ void csr_fill_cse(const int* __restrict__ srcv, const int* __restrict__ dstv,
                             const int* __restrict__ rank,
                             const int* __restrict__ offs, int E,
                             int2* __restrict__ cse) {
    int e = blockIdx.x * blockDim.x + threadIdx.x;
    if (e >= E) return;
    cse[offs[dstv[e]] + rank[e]] = make_int2(srcv[e], e);
}

// ---------- ALL weight pre-packs in one launch ----------
__device__ __forceinline__ void pack_w_job(const float* Wl, const float* Wr, u32* Wb,
                                           int t, int NKS) {
    int lane = t & 63;
    int ks = (t >> 6) % NKS;
    int ct = (t >> 6) / NKS;
    int n = lane & 15, quad = lane >> 4;
    int c = ct * 16 + n;
    const float* W = (c < 64) ? Wl : Wr;
    int cc = c & 63;
    u32* d = Wb + (u64)t * 4;
#pragma unroll
    for (int p = 0; p < 4; p++) {
        int k0 = ks * 32 + quad * 8 + 2 * p;
        d[p] = pack2(W[(u64)k0 * 64 + cc], W[(u64)(k0 + 1) * 64 + cc]);
    }
}
__device__ __forceinline__ void pack_we_job(const float* We, u32* web, int t) {
    int lane = t & 63, ct = t >> 6;
    int n = lane & 15, quad = lane >> 4;
    int c = ct * 16 + n;
    u32* d = web + (u64)t * 4;
#pragma unroll
    for (int p = 0; p < 4; p++) {
        int k0 = quad * 8 + 2 * p;
        d[p] = (k0 + 1 < 16) ? pack2(We[(u64)k0 * 64 + c], We[(u64)(k0 + 1) * 64 + c]) : 0u;
    }
}
__global__ void pack_all(const float* __restrict__ Wl1, const float* __restrict__ Wr1,
                         const float* __restrict__ Wl2, const float* __restrict__ Wr2,
                         const float* __restrict__ We1, const float* __restrict__ We2,
                         u32* __restrict__ wb1, u32* __restrict__ wb2,
                         u32* __restrict__ web1, u32* __restrict__ web2) {
    int t = blockIdx.x * blockDim.x + threadIdx.x;
    if (t < 2048)       pack_w_job(Wl1, Wr1, wb1, t, 4);
    else if (t < 3072)  pack_w_job(Wl2, Wr2, wb2, t - 2048, 2);
    else if (t < 3328)  pack_we_job(We1, web1, t - 3072);
    else if (t < 3584)  pack_we_job(We2, web2, t - 3328);
}

// ---------- MFMA dual GEMM body: [xl|xr] = X @ [Wl|Wr] + [bl|br] (bf16 out) ----------
// Output layout PERMUTED for gat gathers: buf[row][m*4+ct] -> one dwordx2 per gather.
template <int K, bool XF32>
__device__ __forceinline__ void gemm_body(int gblk, const void* __restrict__ Xv,
                                          const u32* __restrict__ Wb,
                                          const float* __restrict__ bl,
                                          const float* __restrict__ br,
                                          int N, u16* __restrict__ xl, u16* __restrict__ xr) {
    constexpr int NKS = K / 32;
    int lane = threadIdx.x & 63;
    int gw = gblk * 4 + (threadIdx.x >> 6);
    int row0 = gw * 16;
    if (row0 >= N) return;
    int m = lane & 15, quad = lane >> 4;

    f32x4 acc[8];
#pragma unroll
    for (int ct = 0; ct < 8; ct++) acc[ct] = (f32x4){0.f, 0.f, 0.f, 0.f};

#pragma unroll
    for (int ks = 0; ks < NKS; ks++) {
        bfrag a;
        if (XF32) {
            const float* xp = (const float*)Xv + (u64)(row0 + m) * K + ks * 32 + quad * 8;
            float4 v0 = *(const float4*)xp;
            float4 v1 = *(const float4*)(xp + 4);
            union { bfrag v; u32 d[4]; } au;
            au.d[0] = pack2(v0.x, v0.y); au.d[1] = pack2(v0.z, v0.w);
            au.d[2] = pack2(v1.x, v1.y); au.d[3] = pack2(v1.z, v1.w);
            a = au.v;
        } else {
            a = *(const bfrag*)((const u16*)Xv + (u64)(row0 + m) * K + ks * 32 + quad * 8);
        }
#pragma unroll
        for (int ct = 0; ct < 8; ct++) {
            bfrag b = *(const bfrag*)(Wb + (u64)((ct * NKS + ks) * 64 + lane) * 4);
            acc[ct] = __builtin_amdgcn_mfma_f32_16x16x32_bf16(a, b, acc[ct], 0, 0, 0);
        }
    }

    float bvl[4], bvr[4];
#pragma unroll
    for (int ct = 0; ct < 4; ct++) { bvl[ct] = bl[ct * 16 + m]; bvr[ct] = br[ct * 16 + m]; }
#pragma unroll
    for (int r = 0; r < 4; r++) {
        int row = row0 + quad * 4 + r;
        uint2 ql, qr;
        ql.x = pack2(acc[0][r] + bvl[0], acc[1][r] + bvl[1]);
        ql.y = pack2(acc[2][r] + bvl[2], acc[3][r] + bvl[3]);
        qr.x = pack2(acc[4][r] + bvr[0], acc[5][r] + bvr[1]);
        qr.y = pack2(acc[6][r] + bvr[2], acc[7][r] + bvr[3]);
        *(uint2*)(xl + (u64)row * 64 + m * 4) = ql;
        *(uint2*)(xr + (u64)row * 64 + m * 4) = qr;
    }
}

__global__ __launch_bounds__(256) void gemm_mfma64(const u16* __restrict__ Xv,
                                                   const u32* __restrict__ Wb,
                                                   const float* __restrict__ bl,
                                                   const float* __restrict__ br,
                                                   int N, u16* __restrict__ xl, u16* __restrict__ xr) {
    gemm_body<64, false>(blockIdx.x, Xv, Wb, bl, br, N, xl, xr);
}

// ---------- FUSED: edge prep (attr conv + rank atomic) || GEMM layer-1 ----------
// Role split 1-in-5: blockIdx.x%5==0 -> GEMM1 block (independent node-side work),
// else edge block. The GEMM's MFMA/compute hides under edge_prep's atomic+HBM
// latency; saves 2 launches and serializes nothing (no data dependence).
__global__ __launch_bounds__(256) void prep_gemm1(const int* __restrict__ dstv,
                                                  const float4* __restrict__ ea, int E,
                                                  int* __restrict__ deg, int* __restrict__ rank,
                                                  uint4* __restrict__ eattr,
                                                  const float* __restrict__ x,
                                                  const u32* __restrict__ wb1,
                                                  const float* __restrict__ bl1,
                                                  const float* __restrict__ br1,
                                                  int N, u16* __restrict__ xl, u16* __restrict__ xr) {
    int g = blockIdx.x / 5;
    int r = blockIdx.x % 5;
    if (r == 0) {
        gemm_body<128, true>(g, x, wb1, bl1, br1, N, xl, xr);
    } else {
        int e = (g * 4 + (r - 1)) * 256 + threadIdx.x;
        if (e >= E) return;
        const float4* s = ea + (u64)e * 4;
        float4 v0 = s[0], v1 = s[1], v2 = s[2], v3 = s[3];
        int d = dstv[e];
        int rk = atomicAdd(&deg[d], 1);
        eattr[(u64)e * 2]     = make_uint4(pack2(v0.x, v0.y), pack2(v0.z, v0.w),
                                           pack2(v1.x, v1.y), pack2(v1.z, v1.w));
        eattr[(u64)e * 2 + 1] = make_uint4(pack2(v2.x, v2.y), pack2(v2.z, v2.w),
                                           pack2(v3.x, v3.y), pack2(v3.z, v3.w));
        rank[e] = rk;
    }
}

// ---------- GATv2 layer: MFMA edge-attr transform, 16 edges per step (r7 path) ----------
// EE[16e x 64c] = EA[16x16] @ We[16x64] via 4x mfma_f32_16x16x32_bf16 (K zero-padded
// to 32). xr folded into MFMA C-operand (broadcast over rows); invalid tail rows then
// produce ee=xr exactly, so eesum = sum(eeX)-4*xr stays exact. A-frag reads eattr[eid]
// (bf16, edge order, L3-resident); eid/src via shfl from the coalesced int2 cse preload.
// xl/xr PERMUTED [row][m*4+ct] -> each src gather is ONE dwordx2.
// D layout: lane(quad,m) reg r -> edge=quad*4+r, chan=ct*16+m.
__global__ __launch_bounds__(256) void gat_layer(const u16* __restrict__ xl, const u16* __restrict__ xr,
                                                 const int* __restrict__ offs,
                                                 const int2* __restrict__ cse,   // {src, eid} per CSR slot
                                                 const u32* __restrict__ eattr,  // 16 bf16 per EDGE
                                                 const u32* __restrict__ web,    // packed We B-frags
                                                 const float* __restrict__ att,  // 64, fp32
                                                 const float* __restrict__ bias, // 64, fp32
                                                 int N, u16* __restrict__ out) {
    const float LOG2E = 1.44269504088896340736f;
    int l = threadIdx.x & 63;
    int m = l & 15, quad = l >> 4;
    int wid = RFL((int)((blockIdx.x * 256 + threadIdx.x) >> 6));
    int nw = gridDim.x * 4;

    bfrag wb[4];
#pragma unroll
    for (int ct = 0; ct < 4; ct++) wb[ct] = *(const bfrag*)(web + (u64)(ct * 64 + l) * 4);

    float att_l = att[l] * LOG2E;
    float att_f[4];
#pragma unroll
    for (int ct = 0; ct < 4; ct++) att_f[ct] = att[ct * 16 + m] * LOG2E;
    float bias_l = bias[l];

    for (int n = wid; n < N; n += nw) {
        int a = RFL(offs[n]);
        int b = RFL(offs[n + 1]);
        float xr_l = bf2f(xr[(u32)(n * 64 + m * 4 + quad)]);
        float xl_self = bf2f(xl[(u32)(n * 64 + m * 4 + quad)]);
        uint2 qxr = *(const uint2*)(xr + (u32)(n * 64 + m * 4));
        float xr_f[4] = {lo16(qxr.x), hi16(qxr.x), lo16(qxr.y), hi16(qxr.y)};

        float o_f[4] = {0.f, 0.f, 0.f, 0.f};
        float ls_f[4] = {0.f, 0.f, 0.f, 0.f};
        float ee_f[4] = {0.f, 0.f, 0.f, 0.f};

        for (int base = a; base < b; base += 64) {
            int cnt64 = b - base; if (cnt64 > 64) cnt64 = 64;
            int idx = base + l;
            int2 sev = cse[idx < b ? idx : b - 1];   // coalesced per-lane preload
            int sv = sev.x, ev = sev.y;

            for (int j = 0; j < cnt64; j += 16) {
                int cnt = cnt64 - j; if (cnt > 16) cnt = 16;
                // --- A-frag: 16 edge rows x 32 bf16 (upper 16 zero), via eid ---
                int em = __shfl(ev, j + m);
                union { bfrag v; u32 d[4]; } au;
                au.d[0] = 0; au.d[1] = 0; au.d[2] = 0; au.d[3] = 0;
                if (quad < 2 && m < cnt)
                    au.v = *(const bfrag*)(eattr + (u64)em * 8 + quad * 4);
                // --- this quad's 4 srcs; one dwordx2 gather each ---
                int jq = j + quad * 4;
                int sr0 = __shfl(sv, jq);
                int sr1 = __shfl(sv, jq + 1);
                int sr2 = __shfl(sv, jq + 2);
                int sr3 = __shfl(sv, jq + 3);
                uint2 g0 = *(const uint2*)(xl + (u32)(sr0 * 64 + m * 4));
                uint2 g1 = *(const uint2*)(xl + (u32)(sr1 * 64 + m * 4));
                uint2 g2 = *(const uint2*)(xl + (u32)(sr2 * 64 + m * 4));
                uint2 g3 = *(const uint2*)(xl + (u32)(sr3 * 64 + m * 4));
                float xv[4][4];
                xv[0][0] = lo16(g0.x); xv[0][1] = hi16(g0.x); xv[0][2] = lo16(g0.y); xv[0][3] = hi16(g0.y);
                xv[1][0] = lo16(g1.x); xv[1][1] = hi16(g1.x); xv[1][2] = lo16(g1.y); xv[1][3] = hi16(g1.y);
                xv[2][0] = lo16(g2.x); xv[2][1] = hi16(g2.x); xv[2][2] = lo16(g2.y); xv[2][3] = hi16(g2.y);
                xv[3][0] = lo16(g3.x); xv[3][1] = hi16(g3.x); xv[3][2] = lo16(g3.y); xv[3][3] = hi16(g3.y);
                // --- MFMA: ee = EA @ We + xr (xr broadcast over rows via C) ---
                f32x4 ee[4];
#pragma unroll
                for (int ct = 0; ct < 4; ct++) {
                    f32x4 c = (f32x4){xr_f[ct], xr_f[ct], xr_f[ct], xr_f[ct]};
                    ee[ct] = __builtin_amdgcn_mfma_f32_16x16x32_bf16(au.v, wb[ct], c, 0, 0, 0);
                }
                // --- eesum (raw ee): invalid rows give eeX = xr exactly ---
#pragma unroll
                for (int ct = 0; ct < 4; ct++)
                    ee_f[ct] += (ee[ct][0] + ee[ct][1]) + (ee[ct][2] + ee[ct][3]) - 4.f * xr_f[ct];
                // --- z, leaky, att-scale ---
                float zz[4][4];
#pragma unroll
                for (int ct = 0; ct < 4; ct++) {
#pragma unroll
                    for (int r = 0; r < 4; r++) {
                        float z = ee[ct][r] + xv[r][ct];
                        z = fmaxf(z, 0.2f * z);
                        zz[ct][r] = z * att_f[ct];
                    }
                }
                // --- 16 interleaved red16 (DPP hazards hidden) ---
#define R16(ctrl) { \
    DPP_ROR_ADD(zz[0][0], ctrl); DPP_ROR_ADD(zz[0][1], ctrl); DPP_ROR_ADD(zz[0][2], ctrl); DPP_ROR_ADD(zz[0][3], ctrl); \
    DPP_ROR_ADD(zz[1][0], ctrl); DPP_ROR_ADD(zz[1][1], ctrl); DPP_ROR_ADD(zz[1][2], ctrl); DPP_ROR_ADD(zz[1][3], ctrl); \
    DPP_ROR_ADD(zz[2][0], ctrl); DPP_ROR_ADD(zz[2][1], ctrl); DPP_ROR_ADD(zz[2][2], ctrl); DPP_ROR_ADD(zz[2][3], ctrl); \
    DPP_ROR_ADD(zz[3][0], ctrl); DPP_ROR_ADD(zz[3][1], ctrl); DPP_ROR_ADD(zz[3][2], ctrl); DPP_ROR_ADD(zz[3][3], ctrl); }
                R16(0x128) R16(0x124) R16(0x122) R16(0x121)
#undef R16
                // --- exp (pre-scaled by log2e -> raw v_exp_f32) ---
                float w[4][4];
#pragma unroll
                for (int ct = 0; ct < 4; ct++) {
#pragma unroll
                    for (int r = 0; r < 4; r++)
                        asm("v_exp_f32 %0, %1" : "=v"(w[ct][r]) : "v"(zz[ct][r]));
                }
                // --- tail mask: zero weights of invalid rows ---
                if (cnt < 16) {
#pragma unroll
                    for (int r = 0; r < 4; r++) {
                        bool ok = (quad * 4 + r) < cnt;
#pragma unroll
                        for (int ct = 0; ct < 4; ct++) w[ct][r] = ok ? w[ct][r] : 0.f;
                    }
                }
                // --- accumulate ---
#pragma unroll
                for (int ct = 0; ct < 4; ct++) {
#pragma unroll
                    for (int r = 0; r < 4; r++) {
                        ls_f[ct] += w[ct][r];
                        o_f[ct] = fmaf(w[ct][r], xv[r][ct], o_f[ct]);
                    }
                }
            }
        }

        // --- cross-quad reduction (edges split 4 per quad) ---
#pragma unroll
        for (int ct = 0; ct < 4; ct++) {
            o_f[ct] += __shfl_xor(o_f[ct], 16);  o_f[ct] += __shfl_xor(o_f[ct], 32);
            ls_f[ct] += __shfl_xor(ls_f[ct], 16); ls_f[ct] += __shfl_xor(ls_f[ct], 32);
            ee_f[ct] += __shfl_xor(ee_f[ct], 16); ee_f[ct] += __shfl_xor(ee_f[ct], 32);
        }
        float o    = (quad & 2) ? ((quad & 1) ? o_f[3] : o_f[2]) : ((quad & 1) ? o_f[1] : o_f[0]);
        float lsum = (quad & 2) ? ((quad & 1) ? ls_f[3] : ls_f[2]) : ((quad & 1) ? ls_f[1] : ls_f[0]);
        float eesum= (quad & 2) ? ((quad & 1) ? ee_f[3] : ee_f[2]) : ((quad & 1) ? ee_f[1] : ee_f[0]);

        // --- self-loop: ee = eesum/deg (mean edge-attr transform), src = n ---
        int deg = b - a;
        float inv = (deg > 0) ? 1.f / (float)deg : 0.f;
        float z = (eesum * inv + xr_l) + xl_self;
        z = fmaxf(z, 0.2f * z);
        float vv = red16(z * att_l);
        float ws;
        asm("v_exp_f32 %0, %1" : "=v"(ws) : "v"(vv));
        lsum += ws;
        o = fmaf(ws, xl_self, o);

        float res = o / (lsum + 1e-16f) + bias_l;
        res = fmaxf(res, 0.f);                        // relu after each GAT layer
        out[(u32)(n * 64 + l)] = f2bf(res);           // natural order (feeds GEMM/MLP)
    }
}

// ---------- MLP head: relu(h @ W1 + b1) @ W2 + b2 -> sigmoid (fp32 out) ----------
__global__ __launch_bounds__(256) void mlp_head(const u16* __restrict__ h,
                                                const float* __restrict__ W1, const float* __restrict__ b1,
                                                const float* __restrict__ W2, const float* __restrict__ b2,
                                                int N, float* __restrict__ out) {
    __shared__ float w1[64 * 16];
    __shared__ float sb1[16];
    __shared__ float w2[16];
    for (int i = threadIdx.x; i < 64 * 16; i += 256) w1[i] = W1[i];
    if (threadIdx.x < 16) { sb1[threadIdx.x] = b1[threadIdx.x]; w2[threadIdx.x] = W2[threadIdx.x]; }
    __syncthreads();
    float b2v = b2[0];
    int n = blockIdx.x * blockDim.x + threadIdx.x;
    if (n < N) {
        float hv[64];
        const u32* hp = (const u32*)(h + (u64)n * 64);
#pragma unroll
        for (int i = 0; i < 32; i++) { u32 u = hp[i]; hv[2 * i] = lo16(u); hv[2 * i + 1] = hi16(u); }
        float z = b2v;
        for (int j = 0; j < 16; j++) {
            float acc = sb1[j];
#pragma unroll
            for (int k = 0; k < 64; k++) acc = fmaf(hv[k], w1[k * 16 + j], acc);
            acc = fmaxf(acc, 0.f);
            z = fmaf(acc, w2[j], z);
        }
        out[n] = 1.f / (1.f + __expf(-z));
    }
}

// ---------- launch ----------
extern "C" void kernel_launch(void* const* d_in, const int* in_sizes, int n_in,
                              void* d_out, int out_size, void* d_ws, size_t ws_size,
                              hipStream_t stream) {
    const float* x    = (const float*)d_in[0];
    const int*   ei   = (const int*)d_in[1];
    const float* ea   = (const float*)d_in[2];
    const float* Wl1  = (const float*)d_in[3];
    const float* bl1  = (const float*)d_in[4];
    const float* Wr1  = (const float*)d_in[5];
    const float* br1  = (const float*)d_in[6];
    const float* We1  = (const float*)d_in[7];
    const float* att1 = (const float*)d_in[8];
    const float* bias1= (const float*)d_in[9];
    const float* Wl2  = (const float*)d_in[10];
    const float* bl2  = (const float*)d_in[11];
    const float* Wr2  = (const float*)d_in[12];
    const float* br2  = (const float*)d_in[13];
    const float* We2  = (const float*)d_in[14];
    const float* att2 = (const float*)d_in[15];
    const float* bias2= (const float*)d_in[16];
    const float* W1   = (const float*)d_in[17];
    const float* b1   = (const float*)d_in[18];
    const float* W2   = (const float*)d_in[19];
    const float* b2   = (const float*)d_in[20];
    float* out = (float*)d_out;

    const int N = in_sizes[0] / 128;
    const int E = in_sizes[1] / 2;
    const int* srcv = ei;
    const int* dstv = ei + E;

    uint8_t* p = (uint8_t*)d_ws;
    auto carve = [&](size_t bytes) -> void* {
        void* r = (void*)p;
        p += (bytes + 255) & ~(size_t)255;
        return r;
    };
    int*  deg     = (int*)carve((size_t)N * 4);
    int*  rank    = (int*)carve((size_t)E * 4);
    int*  offs    = (int*)carve((size_t)(N + 1) * 4);
    int*  partials= (int*)carve(4096);
    int2* cse     = (int2*)carve((size_t)E * 8);    // {src, eid} per CSR slot
    u32*  eattr   = (u32*)carve((size_t)E * 32);    // 16 bf16 per EDGE (edge order)
    u16*  xl      = (u16*)carve((size_t)N * 64 * 2);
    u16*  xr      = (u16*)carve((size_t)N * 64 * 2);
    u16*  hb      = (u16*)carve((size_t)N * 64 * 2);
    u32*  wb1     = (u32*)carve(8 * 4 * 64 * 16);   // K=128 packed W
    u32*  wb2     = (u32*)carve(8 * 2 * 64 * 16);   // K=64 packed W
    u32*  web1    = (u32*)carve(4 * 64 * 4 * 4);    // We1 B-frags
    u32*  web2    = (u32*)carve(4 * 64 * 4 * 4);    // We2 B-frags
    (void)ws_size; (void)n_in; (void)out_size;

    hipMemsetAsync(deg, 0, (size_t)N * 4, stream);

    const int B = 256;
    pack_all<<<14, 256, 0, stream>>>(Wl1, Wr1, Wl2, Wr2, We1, We2, wb1, wb2, web1, web2);

    // fused edge-prep || GEMM1 (independent): 1-in-5 blocks run GEMM1
    int gemm_blocks = (N / 16 + 3) / 4;
    int edge_blocks = (E + B - 1) / B;
    int gmax = gemm_blocks > (edge_blocks + 3) / 4 ? gemm_blocks : (edge_blocks + 3) / 4;
    prep_gemm1<<<gmax * 5, 256, 0, stream>>>(dstv, (const float4*)ea, E, deg, rank,
                                             (uint4*)eattr, x, wb1, bl1, br1, N, xl, xr);

    int nb = (N + SCAN_CHUNK - 1) / SCAN_CHUNK;
    scan_partial<<<nb, SCAN_T, 0, stream>>>(deg, N, partials);
    scan_mid<<<1, 64, 0, stream>>>(partials, nb);
    scan_final<<<nb, SCAN_T, 0, stream>>>(deg, N, partials, offs, E);
    csr_fill_cse<<<edge_blocks, B, 0, stream>>>(srcv, dstv, rank, offs, E, cse);

    // Layer 1 aggregation
    gat_layer<<<8192, 256, 0, stream>>>(xl, xr, offs, cse, eattr, web1,
                                        att1, bias1, N, hb);
    // Layer 2
    gemm_mfma64<<<gemm_blocks, 256, 0, stream>>>(hb, wb2, bl2, br2, N, xl, xr);
    gat_layer<<<8192, 256, 0, stream>>>(xl, xr, offs, cse, eattr, web2,
                                        att2, bias2, N, hb);
    // Head
    mlp_head<<<(N + B - 1) / B, B, 0, stream>>>(hb, W1, b1, W2, b2, N, out);
}